// Round 2
// baseline (7084.520 us; speedup 1.0000x reference)
//
#include <hip/hip_runtime.h>

// Problem constants: T=128, B=128, S=128, H=1024, E=512, V=32000, L=2
#define TT 128
#define BB 128
#define SS 128
#define HH 1024
#define EE 512
#define BH (BB*HH)   // 131072

typedef unsigned short u16;                                   // bf16 bits
typedef __attribute__((ext_vector_type(8))) short s8v;        // MFMA A/B fragment (8 bf16)
typedef __attribute__((ext_vector_type(4))) float f32x4;      // MFMA C/D fragment

__device__ __forceinline__ float b2f(u16 u) {
    union { unsigned int i; float f; } v; v.i = ((unsigned int)u) << 16; return v.f;
}
__device__ __forceinline__ u16 f2b(float f) {
    union { float f; unsigned int i; } v; v.f = f;
    unsigned int x = v.i;
    x = x + 0x7fffu + ((x >> 16) & 1u);   // round-to-nearest-even
    return (u16)(x >> 16);
}
__device__ __forceinline__ float sigm(float x) {
    float t = __expf(-fabsf(x));
    float p = 1.0f / (1.0f + t);
    return x >= 0.0f ? p : 1.0f - p;
}
__device__ __forceinline__ float tanh_(float x) {
    float t = __expf(-2.0f * fabsf(x));
    float r = (1.0f - t) / (1.0f + t);
    return x >= 0.0f ? r : -r;
}

#define MFMA(a, b, c) __builtin_amdgcn_mfma_f32_16x16x32_bf16((a), (b), (c), 0, 0, 0)

// ---------------------------------------------------------------------------
// fp32 -> bf16 bulk convert (n multiple of 4)
// ---------------------------------------------------------------------------
__global__ __launch_bounds__(256)
void cvt_k(const float* __restrict__ s, u16* __restrict__ d, int n)
{
    const int i = (blockIdx.x * 256 + threadIdx.x) * 4;
    if (i < n) {
        const float4 v = *(const float4*)(s + i);
        ushort4 o;
        o.x = f2b(v.x); o.y = f2b(v.y); o.z = f2b(v.z); o.w = f2b(v.w);
        *(ushort4*)(d + i) = o;
    }
}

// ---------------------------------------------------------------------------
// Embedding gather + cast: X[t*B+b, :] = bf16(emb[toks[t,b], :])
// grid = T*B blocks, 128 threads (4 elems each, E=512)
// ---------------------------------------------------------------------------
__global__ __launch_bounds__(128)
void gather_k(const int* __restrict__ toks, const float* __restrict__ emb,
              u16* __restrict__ X)
{
    const int row = blockIdx.x;
    const int tok = toks[row];
    const int c = threadIdx.x * 4;
    const float4 v = *(const float4*)(emb + (size_t)tok * EE + c);
    ushort4 o;
    o.x = f2b(v.x); o.y = f2b(v.y); o.z = f2b(v.z); o.w = f2b(v.w);
    *(ushort4*)(X + (size_t)row * EE + c) = o;
}

// ---------------------------------------------------------------------------
// init: h buffers (slot 0) <- bf16(h0); c state (fp32) <- c0
// ---------------------------------------------------------------------------
__global__ __launch_bounds__(256)
void init_k(const float* __restrict__ h0in, const float* __restrict__ c0in,
            u16* __restrict__ h0buf0, u16* __restrict__ h1buf0,
            float* __restrict__ cst)
{
    const int i = blockIdx.x * 256 + threadIdx.x;   // [0, 2*BH)
    const u16 hb = f2b(h0in[i]);
    if (i < BH) h0buf0[i] = hb;
    else        h1buf0[i - BH] = hb;
    cst[i] = c0in[i];
}

// ---------------------------------------------------------------------------
// LSTM layer step: gates = x @ Wih^T + h @ Whh^T (+biases), cell update.
// A-operands bf16 pre-converted. Block: 2 waves x 16 rows; grid (64, 4).
// If h1out != null also mirrors new h there (layer-1 path).
// ---------------------------------------------------------------------------
__global__ __launch_bounds__(128)
void lstm_k(const u16* __restrict__ X, int KX,
            const u16* __restrict__ Wih, const u16* __restrict__ Whh,
            const float* __restrict__ bih, const float* __restrict__ bhh,
            const u16* __restrict__ hcur, u16* __restrict__ hnxt,
            float* __restrict__ cst, u16* __restrict__ h1out)
{
    const int lane = threadIdx.x & 63;
    const int wave = threadIdx.x >> 6;        // 0..1
    const int l15 = lane & 15, quad = lane >> 4;
    const int j0 = blockIdx.x * 16;
    const int mrow = blockIdx.y * 32 + wave * 16;
    const int arow = mrow + l15;

    f32x4 acc[4];
    #pragma unroll
    for (int g = 0; g < 4; ++g) acc[g] = (f32x4)0.0f;

    // part 1: x-input, K = KX
    {
        const u16* ap  = X + (size_t)arow * KX + quad * 8;
        const u16* bp0 = Wih + (size_t)(0 * HH + j0 + l15) * KX + quad * 8;
        const u16* bp1 = Wih + (size_t)(1 * HH + j0 + l15) * KX + quad * 8;
        const u16* bp2 = Wih + (size_t)(2 * HH + j0 + l15) * KX + quad * 8;
        const u16* bp3 = Wih + (size_t)(3 * HH + j0 + l15) * KX + quad * 8;
        #pragma unroll 4
        for (int kk = 0; kk < KX; kk += 32) {
            s8v a = *(const s8v*)(ap + kk);
            acc[0] = MFMA(a, *(const s8v*)(bp0 + kk), acc[0]);
            acc[1] = MFMA(a, *(const s8v*)(bp1 + kk), acc[1]);
            acc[2] = MFMA(a, *(const s8v*)(bp2 + kk), acc[2]);
            acc[3] = MFMA(a, *(const s8v*)(bp3 + kk), acc[3]);
        }
    }
    // part 2: h-recurrence, K = H
    {
        const u16* ap  = hcur + (size_t)arow * HH + quad * 8;
        const u16* bp0 = Whh + (size_t)(0 * HH + j0 + l15) * HH + quad * 8;
        const u16* bp1 = Whh + (size_t)(1 * HH + j0 + l15) * HH + quad * 8;
        const u16* bp2 = Whh + (size_t)(2 * HH + j0 + l15) * HH + quad * 8;
        const u16* bp3 = Whh + (size_t)(3 * HH + j0 + l15) * HH + quad * 8;
        #pragma unroll 4
        for (int kk = 0; kk < HH; kk += 32) {
            s8v a = *(const s8v*)(ap + kk);
            acc[0] = MFMA(a, *(const s8v*)(bp0 + kk), acc[0]);
            acc[1] = MFMA(a, *(const s8v*)(bp1 + kk), acc[1]);
            acc[2] = MFMA(a, *(const s8v*)(bp2 + kk), acc[2]);
            acc[3] = MFMA(a, *(const s8v*)(bp3 + kk), acc[3]);
        }
    }
    // pointwise cell update (gate order i, f, g, o)
    const int j = j0 + l15;
    const float bi  = bih[0 * HH + j] + bhh[0 * HH + j];
    const float bf_ = bih[1 * HH + j] + bhh[1 * HH + j];
    const float bg  = bih[2 * HH + j] + bhh[2 * HH + j];
    const float bo  = bih[3 * HH + j] + bhh[3 * HH + j];
    #pragma unroll
    for (int r = 0; r < 4; ++r) {
        const int brow = mrow + quad * 4 + r;
        const float gi = acc[0][r] + bi;
        const float gf = acc[1][r] + bf_;
        const float gg = acc[2][r] + bg;
        const float go = acc[3][r] + bo;
        const size_t idx = (size_t)brow * HH + j;
        const float cold = cst[idx];
        const float cn = sigm(gf) * cold + sigm(gi) * tanh_(gg);
        cst[idx] = cn;
        const u16 hb = f2b(sigm(go) * tanh_(cn));
        hnxt[idx] = hb;
        if (h1out) h1out[idx] = hb;
    }
}

// ---------------------------------------------------------------------------
// C[M,N] = act(A1 @ W[:, :K1]^T + A2 @ W[:, K1:]^T + bias)
// A/W bf16, bias fp32. Out: bf16 (Cb) or fp32 (Cf). Tile 64x64, 4 waves.
// ---------------------------------------------------------------------------
__global__ __launch_bounds__(256)
void gemm_bt_k(const u16* __restrict__ A1, int K1,
               const u16* __restrict__ A2, int K2,
               const u16* __restrict__ W, int ldw,
               const float* __restrict__ bias,
               u16* __restrict__ Cb, float* __restrict__ Cf,
               int N, int act)
{
    const int lane = threadIdx.x & 63;
    const int wave = threadIdx.x >> 6;
    const int l15 = lane & 15, quad = lane >> 4;
    const int n0 = blockIdx.x * 64;
    const int mrow = blockIdx.y * 64 + wave * 16;
    const int arow = mrow + l15;

    f32x4 acc[4];
    #pragma unroll
    for (int nt = 0; nt < 4; ++nt) acc[nt] = (f32x4)0.0f;

    const u16* wr0 = W + (size_t)(n0 + 0 * 16 + l15) * ldw + quad * 8;
    const u16* wr1 = W + (size_t)(n0 + 1 * 16 + l15) * ldw + quad * 8;
    const u16* wr2 = W + (size_t)(n0 + 2 * 16 + l15) * ldw + quad * 8;
    const u16* wr3 = W + (size_t)(n0 + 3 * 16 + l15) * ldw + quad * 8;

    {
        const u16* ap = A1 + (size_t)arow * K1 + quad * 8;
        #pragma unroll 4
        for (int kk = 0; kk < K1; kk += 32) {
            s8v a = *(const s8v*)(ap + kk);
            acc[0] = MFMA(a, *(const s8v*)(wr0 + kk), acc[0]);
            acc[1] = MFMA(a, *(const s8v*)(wr1 + kk), acc[1]);
            acc[2] = MFMA(a, *(const s8v*)(wr2 + kk), acc[2]);
            acc[3] = MFMA(a, *(const s8v*)(wr3 + kk), acc[3]);
        }
    }
    if (A2 != nullptr) {
        const u16* ap = A2 + (size_t)arow * K2 + quad * 8;
        #pragma unroll 4
        for (int kk = 0; kk < K2; kk += 32) {
            s8v a = *(const s8v*)(ap + kk);
            acc[0] = MFMA(a, *(const s8v*)(wr0 + K1 + kk), acc[0]);
            acc[1] = MFMA(a, *(const s8v*)(wr1 + K1 + kk), acc[1]);
            acc[2] = MFMA(a, *(const s8v*)(wr2 + K1 + kk), acc[2]);
            acc[3] = MFMA(a, *(const s8v*)(wr3 + K1 + kk), acc[3]);
        }
    }
    #pragma unroll
    for (int nt = 0; nt < 4; ++nt) {
        const int col = n0 + nt * 16 + l15;
        const float bv = bias[col];
        #pragma unroll
        for (int r = 0; r < 4; ++r) {
            const int row = mrow + quad * 4 + r;
            float v = acc[nt][r] + bv;
            if (act) v = tanh_(v);
            if (Cf) Cf[(size_t)row * N + col] = v;
            else    Cb[(size_t)row * N + col] = f2b(v);
        }
    }
}

// ---------------------------------------------------------------------------
// Attention: per block (b, 16-t chunk): scores = gamma @ ctx^T (MFMA, ctx
// converted on the fly), softmax over S in LDS, ct = w @ ctx (fp32 vector).
// ---------------------------------------------------------------------------
__global__ __launch_bounds__(256)
void attn_k(const u16* __restrict__ gamma, const float* __restrict__ ctx,
            u16* __restrict__ ctall)
{
    const int b = blockIdx.x;
    const int t0 = blockIdx.y * 16;
    const int tid = threadIdx.x;
    const int lane = tid & 63, wave = tid >> 6;
    const int l15 = lane & 15, quad = lane >> 4;

    __shared__ float sw[16 * SS];

    // phase A: scores[t, s], s in [wave*32, wave*32+32)
    {
        f32x4 acc0 = (f32x4)0.0f, acc1 = (f32x4)0.0f;
        const u16*   ap  = gamma + ((size_t)(t0 + l15) * BB + b) * HH + quad * 8;
        const float* bp0 = ctx + ((size_t)b * SS + (wave * 32 + l15)) * HH + quad * 8;
        const float* bp1 = ctx + ((size_t)b * SS + (wave * 32 + 16 + l15)) * HH + quad * 8;
        for (int kk = 0; kk < HH; kk += 32) {
            s8v a = *(const s8v*)(ap + kk);
            float4 u0 = *(const float4*)(bp0 + kk);
            float4 u1 = *(const float4*)(bp0 + kk + 4);
            s8v bv;
            bv[0] = (short)f2b(u0.x); bv[1] = (short)f2b(u0.y);
            bv[2] = (short)f2b(u0.z); bv[3] = (short)f2b(u0.w);
            bv[4] = (short)f2b(u1.x); bv[5] = (short)f2b(u1.y);
            bv[6] = (short)f2b(u1.z); bv[7] = (short)f2b(u1.w);
            acc0 = MFMA(a, bv, acc0);
            float4 w0 = *(const float4*)(bp1 + kk);
            float4 w1 = *(const float4*)(bp1 + kk + 4);
            s8v cv;
            cv[0] = (short)f2b(w0.x); cv[1] = (short)f2b(w0.y);
            cv[2] = (short)f2b(w0.z); cv[3] = (short)f2b(w0.w);
            cv[4] = (short)f2b(w1.x); cv[5] = (short)f2b(w1.y);
            cv[6] = (short)f2b(w1.z); cv[7] = (short)f2b(w1.w);
            acc1 = MFMA(a, cv, acc1);
        }
        #pragma unroll
        for (int r = 0; r < 4; ++r) {
            const int trow = quad * 4 + r;
            sw[trow * SS + wave * 32 + l15] = acc0[r];
            sw[trow * SS + wave * 32 + 16 + l15] = acc1[r];
        }
    }
    __syncthreads();

    // phase B: softmax along s (16 threads per row, 8 cols each)
    {
        const int row = tid >> 4, c0 = tid & 15;
        float e[8];
        float m = -1e30f;
        #pragma unroll
        for (int k = 0; k < 8; ++k) { e[k] = sw[row * SS + c0 + k * 16]; m = fmaxf(m, e[k]); }
        #pragma unroll
        for (int off = 8; off >= 1; off >>= 1) m = fmaxf(m, __shfl_xor(m, off));
        float s = 0.0f;
        #pragma unroll
        for (int k = 0; k < 8; ++k) { e[k] = __expf(e[k] - m); s += e[k]; }
        #pragma unroll
        for (int off = 8; off >= 1; off >>= 1) s += __shfl_xor(s, off);
        const float inv = 1.0f / s;
        #pragma unroll
        for (int k = 0; k < 8; ++k) sw[row * SS + c0 + k * 16] = e[k] * inv;
    }
    __syncthreads();

    // phase C: ct[t, h] = sum_s w[t,s] * ctx[b,s,h] (fp32)
    {
        const int h0 = tid * 4;
        float a[16][4];
        #pragma unroll
        for (int t = 0; t < 16; ++t)
            #pragma unroll
            for (int q = 0; q < 4; ++q) a[t][q] = 0.0f;

        const float* cp = ctx + (size_t)b * SS * HH + h0;
        for (int s = 0; s < SS; ++s) {
            const float4 cv = *(const float4*)(cp + (size_t)s * HH);
            #pragma unroll
            for (int t = 0; t < 16; ++t) {
                const float wgt = sw[t * SS + s];
                a[t][0] += wgt * cv.x;
                a[t][1] += wgt * cv.y;
                a[t][2] += wgt * cv.z;
                a[t][3] += wgt * cv.w;
            }
        }
        #pragma unroll
        for (int t = 0; t < 16; ++t) {
            u16* op = ctall + ((size_t)(t0 + t) * BB + b) * HH + h0;
            #pragma unroll
            for (int q = 0; q < 4; ++q) op[q] = f2b(a[t][q]);
        }
    }
}

// ---------------------------------------------------------------------------
// final: hT / cT tail of d_out (fp32)
// ---------------------------------------------------------------------------
__global__ __launch_bounds__(256)
void final_k(const u16* __restrict__ h0b, const u16* __restrict__ h1b,
             const float* __restrict__ cst,
             float* __restrict__ outh, float* __restrict__ outc)
{
    const int i = blockIdx.x * 256 + threadIdx.x;   // [0, 2*BH)
    outh[i] = b2f((i < BH) ? h0b[i] : h1b[i - BH]);
    outc[i] = cst[i];
}

// ---------------------------------------------------------------------------
extern "C" void kernel_launch(void* const* d_in, const int* in_sizes, int n_in,
                              void* d_out, int out_size, void* d_ws, size_t ws_size,
                              hipStream_t stream)
{
    const int*   toks = (const int*)d_in[0];
    const float* h0in = (const float*)d_in[1];
    const float* c0in = (const float*)d_in[2];
    const float* ctx  = (const float*)d_in[3];
    const float* emb  = (const float*)d_in[4];
    const float* Wih0 = (const float*)d_in[5];
    const float* Whh0 = (const float*)d_in[6];
    const float* bih0 = (const float*)d_in[7];
    const float* bhh0 = (const float*)d_in[8];
    const float* Wih1 = (const float*)d_in[9];
    const float* Whh1 = (const float*)d_in[10];
    const float* bih1 = (const float*)d_in[11];
    const float* bhh1 = (const float*)d_in[12];
    const float* attW = (const float*)d_in[13];
    const float* attb = (const float*)d_in[14];
    const float* outW = (const float*)d_in[15];
    const float* outb = (const float*)d_in[16];

    // workspace layout (~148 MB)
    u16*   h0buf = (u16*)d_ws;                 // 2*BH
    u16*   h1buf = h0buf + 2 * BH;             // 2*BH
    float* cst   = (float*)(h1buf + 2 * BH);   // 2*BH fp32
    u16*   Xb    = (u16*)(cst + 2 * BH);       // T*B*E
    u16*   Wih0b = Xb + (size_t)TT * BB * EE;  // 4H*E
    u16*   Whh0b = Wih0b + (size_t)4 * HH * EE;
    u16*   Wih1b = Whh0b + (size_t)4 * HH * HH;
    u16*   Whh1b = Wih1b + (size_t)4 * HH * HH;
    u16*   attWb = Whh1b + (size_t)4 * HH * HH;
    u16*   outWb = attWb + (size_t)HH * HH;
    u16*   H1all = outWb + (size_t)HH * 2 * HH;
    u16*   gammaA = H1all + (size_t)TT * BH;
    u16*   ctall  = gammaA + (size_t)TT * BH;

    // one-time fp32 -> bf16 conversions
    auto cvt = [&](const float* s, u16* d, int n) {
        cvt_k<<<dim3((n / 4 + 255) / 256), 256, 0, stream>>>(s, d, n);
    };
    cvt(Wih0, Wih0b, 4 * HH * EE);
    cvt(Whh0, Whh0b, 4 * HH * HH);
    cvt(Wih1, Wih1b, 4 * HH * HH);
    cvt(Whh1, Whh1b, 4 * HH * HH);
    cvt(attW, attWb, HH * HH);
    cvt(outW, outWb, HH * 2 * HH);

    gather_k<<<dim3(TT * BB), 128, 0, stream>>>(toks, emb, Xb);
    init_k<<<dim3(2 * BH / 256), 256, 0, stream>>>(h0in, c0in, h0buf, h1buf, cst);

    for (int t = 0; t < TT; ++t) {
        const int cur = t & 1, nxt = cur ^ 1;
        lstm_k<<<dim3(64, 4), 128, 0, stream>>>(
            Xb + (size_t)t * BB * EE, EE, Wih0b, Whh0b, bih0, bhh0,
            h0buf + (size_t)cur * BH, h0buf + (size_t)nxt * BH, cst, nullptr);
        lstm_k<<<dim3(64, 4), 128, 0, stream>>>(
            h0buf + (size_t)nxt * BH, HH, Wih1b, Whh1b, bih1, bhh1,
            h1buf + (size_t)cur * BH, h1buf + (size_t)nxt * BH,
            cst + BH, H1all + (size_t)t * BH);
    }

    // gamma = H1all @ attW^T + attb  (bf16 out)
    gemm_bt_k<<<dim3(HH / 64, (TT * BB) / 64), 256, 0, stream>>>(
        H1all, HH, nullptr, 0, attWb, HH, attb, gammaA, nullptr, HH, 0);

    // scores -> softmax -> ct
    attn_k<<<dim3(BB, TT / 16), 256, 0, stream>>>(gammaA, ctx, ctall);

    // out = tanh([ct, h1] @ outW^T + outb)  (fp32 out -> d_out)
    float* outp = (float*)d_out;
    gemm_bt_k<<<dim3(HH / 64, (TT * BB) / 64), 256, 0, stream>>>(
        ctall, HH, H1all, HH, outWb, 2 * HH, outb, nullptr, outp, HH, 1);

    // hT, cT tail
    final_k<<<dim3(2 * BH / 256), 256, 0, stream>>>(
        h0buf, h1buf, cst,
        outp + (size_t)TT * BH, outp + (size_t)TT * BH + 2 * BH);
}

// Round 3
// 5234.035 us; speedup vs baseline: 1.3535x; 1.3535x over previous
//
#include <hip/hip_runtime.h>

// Problem constants: T=128, B=128, S=128, H=1024, E=512, V=32000, L=2
#define TT 128
#define BB 128
#define SS 128
#define HH 1024
#define EE 512
#define BH (BB*HH)   // 131072

typedef unsigned short u16;                                   // bf16 bits
typedef __attribute__((ext_vector_type(8))) short s8v;        // MFMA A/B fragment (8 bf16)
typedef __attribute__((ext_vector_type(4))) float f32x4;      // MFMA C/D fragment

__device__ __forceinline__ float b2f(u16 u) {
    union { unsigned int i; float f; } v; v.i = ((unsigned int)u) << 16; return v.f;
}
__device__ __forceinline__ u16 f2b(float f) {
    union { float f; unsigned int i; } v; v.f = f;
    unsigned int x = v.i;
    x = x + 0x7fffu + ((x >> 16) & 1u);   // round-to-nearest-even
    return (u16)(x >> 16);
}
__device__ __forceinline__ float sigm(float x) {
    float t = __expf(-fabsf(x));
    float p = 1.0f / (1.0f + t);
    return x >= 0.0f ? p : 1.0f - p;
}
__device__ __forceinline__ float tanh_(float x) {
    float t = __expf(-2.0f * fabsf(x));
    float r = (1.0f - t) / (1.0f + t);
    return x >= 0.0f ? r : -r;
}

#define MFMA(a, b, c) __builtin_amdgcn_mfma_f32_16x16x32_bf16((a), (b), (c), 0, 0, 0)

// ---------------------------------------------------------------------------
// fp32 -> bf16 bulk convert (n multiple of 4)
// ---------------------------------------------------------------------------
__global__ __launch_bounds__(256)
void cvt_k(const float* __restrict__ s, u16* __restrict__ d, int n)
{
    const int i = (blockIdx.x * 256 + threadIdx.x) * 4;
    if (i < n) {
        const float4 v = *(const float4*)(s + i);
        ushort4 o;
        o.x = f2b(v.x); o.y = f2b(v.y); o.z = f2b(v.z); o.w = f2b(v.w);
        *(ushort4*)(d + i) = o;
    }
}

// ---------------------------------------------------------------------------
// Embedding gather + cast: X[t*B+b, :] = bf16(emb[toks[t,b], :])
// ---------------------------------------------------------------------------
__global__ __launch_bounds__(128)
void gather_k(const int* __restrict__ toks, const float* __restrict__ emb,
              u16* __restrict__ X)
{
    const int row = blockIdx.x;
    const int tok = toks[row];
    const int c = threadIdx.x * 4;
    const float4 v = *(const float4*)(emb + (size_t)tok * EE + c);
    ushort4 o;
    o.x = f2b(v.x); o.y = f2b(v.y); o.z = f2b(v.z); o.w = f2b(v.w);
    *(ushort4*)(X + (size_t)row * EE + c) = o;
}

// ---------------------------------------------------------------------------
// init: h buffers (slot 0) <- bf16(h0); barrier counter <- 0
// ---------------------------------------------------------------------------
__global__ __launch_bounds__(256)
void init_k(const float* __restrict__ h0in,
            u16* __restrict__ h0buf0, u16* __restrict__ h1buf0,
            int* __restrict__ barcnt)
{
    const int i = blockIdx.x * 256 + threadIdx.x;   // [0, 2*BH)
    const u16 hb = f2b(h0in[i]);
    if (i < BH) h0buf0[i] = hb;
    else        h1buf0[i - BH] = hb;
    if (i == 0) *barcnt = 0;
}

// ---------------------------------------------------------------------------
// Persistent fused 2-layer LSTM scan. 256 blocks (1/CU) x 512 threads.
// Block bk owns output cols j0=bk*4..+3 of BOTH layers; weights for its 16
// gate-cols/layer live in LDS (loaded once, fp32->bf16, swizzled
// [kchunk][quad][n][8] so the MFMA B-fragment is one contiguous ds_read_b128).
// Phase p: cell0(step p) and cell1(step p-1) — both consume h0^{(p)}, whose
// A-fragments are loaded once and feed both layers' MFMAs. One global
// barrier per phase (sense-free monotonically increasing counter); the
// barrier-independent x-part GEMM runs before the wait to hide its latency.
// c-state in registers (fp32); h round-trips through global as bf16.
// ---------------------------------------------------------------------------
__global__ __launch_bounds__(512, 1)
void scan_k(const float* __restrict__ Wih0, const float* __restrict__ Whh0,
            const float* __restrict__ Wih1, const float* __restrict__ Whh1,
            const float* __restrict__ bih0, const float* __restrict__ bhh0,
            const float* __restrict__ bih1, const float* __restrict__ bhh1,
            const float* __restrict__ c0in,
            const u16* __restrict__ Xb,
            u16* __restrict__ h0buf,    // 2 slots of BH
            u16* __restrict__ h1buf,    // 2 slots of BH
            u16* __restrict__ H1all,    // T * BH
            float* __restrict__ outT,   // d_out + T*BH: [hT (2BH), cT (2BH)]
            int* __restrict__ barcnt)
{
    extern __shared__ u16 lds[];
    u16* W0x = lds;                     // 16*4*16*8  =  8192 u16 (16 KB)
    u16* W0h = W0x + 16*4*16*8;         // 32*4*16*8  = 16384 u16 (32 KB)
    u16* W1x = W0h + 32*4*16*8;         //            = 16384 u16 (32 KB)
    u16* W1h = W1x + 32*4*16*8;         //            = 16384 u16 (32 KB)
    float* gst = (float*)(W1h + 32*4*16*8);  // 8*16*20 = 2560 fp32 (10 KB)

    const int tid  = threadIdx.x;
    const int bk   = blockIdx.x;
    const int j0   = bk * 4;
    const int lane = tid & 63;
    const int w    = tid >> 6;          // wave 0..7  (m-tile = w)
    const int l15  = lane & 15, quad = lane >> 4;

    // ---- one-time: weights -> LDS (fp32 -> bf16, swizzled) ----
    auto loadW = [&](const float* src, int K, u16* dst) {
        const int ntup = (K / 32) * 4 * 16;
        for (int idx = tid; idx < ntup; idx += 512) {
            const int n = idx & 15, q = (idx >> 4) & 3, kc = idx >> 6;
            const int col = ((n >> 2) * HH) + j0 + (n & 3);   // gate*H + j
            const float* sp = src + (size_t)col * K + kc * 32 + q * 8;
            const float4 v0 = *(const float4*)(sp);
            const float4 v1 = *(const float4*)(sp + 4);
            u16* dp = dst + (size_t)idx * 8;
            dp[0] = f2b(v0.x); dp[1] = f2b(v0.y); dp[2] = f2b(v0.z); dp[3] = f2b(v0.w);
            dp[4] = f2b(v1.x); dp[5] = f2b(v1.y); dp[6] = f2b(v1.z); dp[7] = f2b(v1.w);
        }
    };
    loadW(Wih0, EE, W0x);
    loadW(Whh0, HH, W0h);
    loadW(Wih1, HH, W1x);
    loadW(Whh1, HH, W1h);

    // pointwise thread mapping: tid -> (row, output col)
    const int prow = tid >> 2;          // 0..127
    const int pjj  = tid & 3;
    const int pj   = j0 + pjj;
    const int pw   = prow >> 4, pr16 = prow & 15;

    float c0 = c0in[(size_t)0 * BH + (size_t)prow * HH + pj];
    float c1 = c0in[(size_t)1 * BH + (size_t)prow * HH + pj];
    float b0[4], b1[4];
    #pragma unroll
    for (int g = 0; g < 4; ++g) {
        b0[g] = bih0[g * HH + pj] + bhh0[g * HH + pj];
        b1[g] = bih1[g * HH + pj] + bhh1[g * HH + pj];
    }

    __syncthreads();   // LDS weights ready

    const int arow = w * 16 + l15;      // this lane's A-row (batch row)

    for (int p = 0; p <= TT; ++p) {
        f32x4 acc0 = (f32x4)0.0f, acc1 = (f32x4)0.0f;

        // (a) x-part of layer 0 — static data, runs before the barrier wait
        if (p < TT) {
            const u16* ap = Xb + ((size_t)p * BB + arow) * EE + quad * 8;
            #pragma unroll 4
            for (int kc = 0; kc < 16; ++kc) {
                s8v a = *(const s8v*)(ap + kc * 32);
                s8v b = *(const s8v*)(W0x + ((size_t)(kc * 4 + quad) * 16 + l15) * 8);
                acc0 = MFMA(a, b, acc0);
            }
        }

        // (b) wait for previous phase's h writes (device-scope acquire)
        if (p > 0) {
            if (tid == 0) {
                const int target = 256 * p;
                while (__hip_atomic_load(barcnt, __ATOMIC_RELAXED,
                                         __HIP_MEMORY_SCOPE_AGENT) < target) {
                    __builtin_amdgcn_s_sleep(4);
                }
                __threadfence();   // acquire: inv stale L1/L2
            }
            __syncthreads();
        }

        // (c) h-dependent GEMMs
        const u16* h0p = h0buf + (size_t)(p & 1) * BH;   // h0^{(p)}
        {
            const u16* ap = h0p + (size_t)arow * HH + quad * 8;
            if (p == 0) {
                #pragma unroll 4
                for (int kc = 0; kc < 32; ++kc) {
                    s8v a = *(const s8v*)(ap + kc * 32);
                    s8v b = *(const s8v*)(W0h + ((size_t)(kc * 4 + quad) * 16 + l15) * 8);
                    acc0 = MFMA(a, b, acc0);
                }
            } else if (p == TT) {
                #pragma unroll 4
                for (int kc = 0; kc < 32; ++kc) {
                    s8v a = *(const s8v*)(ap + kc * 32);
                    s8v b = *(const s8v*)(W1x + ((size_t)(kc * 4 + quad) * 16 + l15) * 8);
                    acc1 = MFMA(a, b, acc1);
                }
            } else {
                #pragma unroll 4
                for (int kc = 0; kc < 32; ++kc) {
                    s8v a = *(const s8v*)(ap + kc * 32);
                    s8v b0v = *(const s8v*)(W0h + ((size_t)(kc * 4 + quad) * 16 + l15) * 8);
                    s8v b1v = *(const s8v*)(W1x + ((size_t)(kc * 4 + quad) * 16 + l15) * 8);
                    acc0 = MFMA(a, b0v, acc0);
                    acc1 = MFMA(a, b1v, acc1);
                }
            }
        }
        if (p > 0) {   // h1 recurrence
            const u16* ap = h1buf + (size_t)((p - 1) & 1) * BH + (size_t)arow * HH + quad * 8;
            #pragma unroll 4
            for (int kc = 0; kc < 32; ++kc) {
                s8v a = *(const s8v*)(ap + kc * 32);
                s8v b = *(const s8v*)(W1h + ((size_t)(kc * 4 + quad) * 16 + l15) * 8);
                acc1 = MFMA(a, b, acc1);
            }
        }

        // (d) pointwise — layer 0
        if (p < TT) {
            #pragma unroll
            for (int r = 0; r < 4; ++r)
                gst[w * 320 + (quad * 4 + r) * 20 + l15] = acc0[r];
            __syncthreads();
            const float* gr = gst + pw * 320 + pr16 * 20;
            const float gi = gr[0 + pjj]  + b0[0];
            const float gf = gr[4 + pjj]  + b0[1];
            const float gg = gr[8 + pjj]  + b0[2];
            const float go = gr[12 + pjj] + b0[3];
            c0 = sigm(gf) * c0 + sigm(gi) * tanh_(gg);
            const float h = sigm(go) * tanh_(c0);
            h0buf[(size_t)((p + 1) & 1) * BH + (size_t)prow * HH + pj] = f2b(h);
            if (p == TT - 1) {
                outT[(size_t)0 * BH + (size_t)prow * HH + pj] = h;    // hT layer0
                outT[(size_t)2 * BH + (size_t)prow * HH + pj] = c0;   // cT layer0
            }
            __syncthreads();   // before gst reuse
        }
        // pointwise — layer 1
        if (p > 0) {
            #pragma unroll
            for (int r = 0; r < 4; ++r)
                gst[w * 320 + (quad * 4 + r) * 20 + l15] = acc1[r];
            __syncthreads();
            const float* gr = gst + pw * 320 + pr16 * 20;
            const float gi = gr[0 + pjj]  + b1[0];
            const float gf = gr[4 + pjj]  + b1[1];
            const float gg = gr[8 + pjj]  + b1[2];
            const float go = gr[12 + pjj] + b1[3];
            c1 = sigm(gf) * c1 + sigm(gi) * tanh_(gg);
            const float h = sigm(go) * tanh_(c1);
            const u16 hb = f2b(h);
            h1buf[(size_t)(p & 1) * BH + (size_t)prow * HH + pj] = hb;
            H1all[(size_t)(p - 1) * BH + (size_t)prow * HH + pj] = hb;
            if (p == TT) {
                outT[(size_t)1 * BH + (size_t)prow * HH + pj] = h;    // hT layer1
                outT[(size_t)3 * BH + (size_t)prow * HH + pj] = c1;   // cT layer1
            }
            __syncthreads();
        }

        // (e) arrive (device-scope release)
        if (tid == 0) {
            __threadfence();
            __hip_atomic_fetch_add(barcnt, 1, __ATOMIC_RELAXED,
                                   __HIP_MEMORY_SCOPE_AGENT);
        }
    }
}

// ---------------------------------------------------------------------------
// C[M,N] = act(A1 @ W[:, :K1]^T + A2 @ W[:, K1:]^T + bias)
// A/W bf16, bias fp32. Out: bf16 (Cb) or fp32 (Cf). Tile 64x64, 4 waves.
// ---------------------------------------------------------------------------
__global__ __launch_bounds__(256)
void gemm_bt_k(const u16* __restrict__ A1, int K1,
               const u16* __restrict__ A2, int K2,
               const u16* __restrict__ W, int ldw,
               const float* __restrict__ bias,
               u16* __restrict__ Cb, float* __restrict__ Cf,
               int N, int act)
{
    const int lane = threadIdx.x & 63;
    const int wave = threadIdx.x >> 6;
    const int l15 = lane & 15, quad = lane >> 4;
    const int n0 = blockIdx.x * 64;
    const int mrow = blockIdx.y * 64 + wave * 16;
    const int arow = mrow + l15;

    f32x4 acc[4];
    #pragma unroll
    for (int nt = 0; nt < 4; ++nt) acc[nt] = (f32x4)0.0f;

    const u16* wr0 = W + (size_t)(n0 + 0 * 16 + l15) * ldw + quad * 8;
    const u16* wr1 = W + (size_t)(n0 + 1 * 16 + l15) * ldw + quad * 8;
    const u16* wr2 = W + (size_t)(n0 + 2 * 16 + l15) * ldw + quad * 8;
    const u16* wr3 = W + (size_t)(n0 + 3 * 16 + l15) * ldw + quad * 8;

    {
        const u16* ap = A1 + (size_t)arow * K1 + quad * 8;
        #pragma unroll 4
        for (int kk = 0; kk < K1; kk += 32) {
            s8v a = *(const s8v*)(ap + kk);
            acc[0] = MFMA(a, *(const s8v*)(wr0 + kk), acc[0]);
            acc[1] = MFMA(a, *(const s8v*)(wr1 + kk), acc[1]);
            acc[2] = MFMA(a, *(const s8v*)(wr2 + kk), acc[2]);
            acc[3] = MFMA(a, *(const s8v*)(wr3 + kk), acc[3]);
        }
    }
    if (A2 != nullptr) {
        const u16* ap = A2 + (size_t)arow * K2 + quad * 8;
        #pragma unroll 4
        for (int kk = 0; kk < K2; kk += 32) {
            s8v a = *(const s8v*)(ap + kk);
            acc[0] = MFMA(a, *(const s8v*)(wr0 + K1 + kk), acc[0]);
            acc[1] = MFMA(a, *(const s8v*)(wr1 + K1 + kk), acc[1]);
            acc[2] = MFMA(a, *(const s8v*)(wr2 + K1 + kk), acc[2]);
            acc[3] = MFMA(a, *(const s8v*)(wr3 + K1 + kk), acc[3]);
        }
    }
    #pragma unroll
    for (int nt = 0; nt < 4; ++nt) {
        const int col = n0 + nt * 16 + l15;
        const float bv = bias[col];
        #pragma unroll
        for (int r = 0; r < 4; ++r) {
            const int row = mrow + quad * 4 + r;
            float v = acc[nt][r] + bv;
            if (act) v = tanh_(v);
            if (Cf) Cf[(size_t)row * N + col] = v;
            else    Cb[(size_t)row * N + col] = f2b(v);
        }
    }
}

// ---------------------------------------------------------------------------
// Attention: per block (b, 16-t chunk): scores = gamma @ ctx^T (MFMA, ctx
// cast on the fly), softmax over S in LDS, ct = w @ ctx (fp32 vector).
// ---------------------------------------------------------------------------
__global__ __launch_bounds__(256)
void attn_k(const u16* __restrict__ gamma, const float* __restrict__ ctx,
            u16* __restrict__ ctall)
{
    const int b = blockIdx.x;
    const int t0 = blockIdx.y * 16;
    const int tid = threadIdx.x;
    const int lane = tid & 63, wave = tid >> 6;
    const int l15 = lane & 15, quad = lane >> 4;

    __shared__ float sw[16 * SS];

    {
        f32x4 acc0 = (f32x4)0.0f, acc1 = (f32x4)0.0f;
        const u16*   ap  = gamma + ((size_t)(t0 + l15) * BB + b) * HH + quad * 8;
        const float* bp0 = ctx + ((size_t)b * SS + (wave * 32 + l15)) * HH + quad * 8;
        const float* bp1 = ctx + ((size_t)b * SS + (wave * 32 + 16 + l15)) * HH + quad * 8;
        for (int kk = 0; kk < HH; kk += 32) {
            s8v a = *(const s8v*)(ap + kk);
            float4 u0 = *(const float4*)(bp0 + kk);
            float4 u1 = *(const float4*)(bp0 + kk + 4);
            s8v bv;
            bv[0] = (short)f2b(u0.x); bv[1] = (short)f2b(u0.y);
            bv[2] = (short)f2b(u0.z); bv[3] = (short)f2b(u0.w);
            bv[4] = (short)f2b(u1.x); bv[5] = (short)f2b(u1.y);
            bv[6] = (short)f2b(u1.z); bv[7] = (short)f2b(u1.w);
            acc0 = MFMA(a, bv, acc0);
            float4 w0 = *(const float4*)(bp1 + kk);
            float4 w1 = *(const float4*)(bp1 + kk + 4);
            s8v cv;
            cv[0] = (short)f2b(w0.x); cv[1] = (short)f2b(w0.y);
            cv[2] = (short)f2b(w0.z); cv[3] = (short)f2b(w0.w);
            cv[4] = (short)f2b(w1.x); cv[5] = (short)f2b(w1.y);
            cv[6] = (short)f2b(w1.z); cv[7] = (short)f2b(w1.w);
            acc1 = MFMA(a, cv, acc1);
        }
        #pragma unroll
        for (int r = 0; r < 4; ++r) {
            const int trow = quad * 4 + r;
            sw[trow * SS + wave * 32 + l15] = acc0[r];
            sw[trow * SS + wave * 32 + 16 + l15] = acc1[r];
        }
    }
    __syncthreads();

    {
        const int row = tid >> 4, c0 = tid & 15;
        float e[8];
        float m = -1e30f;
        #pragma unroll
        for (int k = 0; k < 8; ++k) { e[k] = sw[row * SS + c0 + k * 16]; m = fmaxf(m, e[k]); }
        #pragma unroll
        for (int off = 8; off >= 1; off >>= 1) m = fmaxf(m, __shfl_xor(m, off));
        float s = 0.0f;
        #pragma unroll
        for (int k = 0; k < 8; ++k) { e[k] = __expf(e[k] - m); s += e[k]; }
        #pragma unroll
        for (int off = 8; off >= 1; off >>= 1) s += __shfl_xor(s, off);
        const float inv = 1.0f / s;
        #pragma unroll
        for (int k = 0; k < 8; ++k) sw[row * SS + c0 + k * 16] = e[k] * inv;
    }
    __syncthreads();

    {
        const int h0 = tid * 4;
        float a[16][4];
        #pragma unroll
        for (int t = 0; t < 16; ++t)
            #pragma unroll
            for (int q = 0; q < 4; ++q) a[t][q] = 0.0f;

        const float* cp = ctx + (size_t)b * SS * HH + h0;
        for (int s = 0; s < SS; ++s) {
            const float4 cv = *(const float4*)(cp + (size_t)s * HH);
            #pragma unroll
            for (int t = 0; t < 16; ++t) {
                const float wgt = sw[t * SS + s];
                a[t][0] += wgt * cv.x;
                a[t][1] += wgt * cv.y;
                a[t][2] += wgt * cv.z;
                a[t][3] += wgt * cv.w;
            }
        }
        #pragma unroll
        for (int t = 0; t < 16; ++t) {
            u16* op = ctall + ((size_t)(t0 + t) * BB + b) * HH + h0;
            #pragma unroll
            for (int q = 0; q < 4; ++q) op[q] = f2b(a[t][q]);
        }
    }
}

// ---------------------------------------------------------------------------
extern "C" void kernel_launch(void* const* d_in, const int* in_sizes, int n_in,
                              void* d_out, int out_size, void* d_ws, size_t ws_size,
                              hipStream_t stream)
{
    const int*   toks = (const int*)d_in[0];
    const float* h0in = (const float*)d_in[1];
    const float* c0in = (const float*)d_in[2];
    const float* ctx  = (const float*)d_in[3];
    const float* emb  = (const float*)d_in[4];
    const float* Wih0 = (const float*)d_in[5];
    const float* Whh0 = (const float*)d_in[6];
    const float* bih0 = (const float*)d_in[7];
    const float* bhh0 = (const float*)d_in[8];
    const float* Wih1 = (const float*)d_in[9];
    const float* Whh1 = (const float*)d_in[10];
    const float* bih1 = (const float*)d_in[11];
    const float* bhh1 = (const float*)d_in[12];
    const float* attW = (const float*)d_in[13];
    const float* attb = (const float*)d_in[14];
    const float* outW = (const float*)d_in[15];
    const float* outb = (const float*)d_in[16];

    // workspace layout (~119 MB)
    u16*   h0buf = (u16*)d_ws;                  // 2*BH
    u16*   h1buf = h0buf + 2 * BH;              // 2*BH
    int*   barcnt = (int*)(h1buf + 2 * BH);     // 1 int (padded to 64)
    u16*   Xb    = (u16*)(barcnt + 64);         // T*B*E
    u16*   H1all = Xb + (size_t)TT * BB * EE;   // T*BH
    u16*   gammaA = H1all + (size_t)TT * BH;    // T*BH
    u16*   ctall  = gammaA + (size_t)TT * BH;   // T*BH
    u16*   attWb = ctall + (size_t)TT * BH;     // H*H
    u16*   outWb = attWb + (size_t)HH * HH;     // H*2H

    // one-time conversions for the batched tail
    cvt_k<<<dim3((HH * HH / 4 + 255) / 256), 256, 0, stream>>>(attW, attWb, HH * HH);
    cvt_k<<<dim3((2 * HH * HH / 4 + 255) / 256), 256, 0, stream>>>(outW, outWb, 2 * HH * HH);

    gather_k<<<dim3(TT * BB), 128, 0, stream>>>(toks, emb, Xb);
    init_k<<<dim3(2 * BH / 256), 256, 0, stream>>>(h0in, h0buf, h1buf, barcnt);

    // persistent fused LSTM scan (writes H1all + hT/cT tail of d_out)
    float* outp = (float*)d_out;
    const int ldsBytes = (16*4*16*8 + 3 * 32*4*16*8) * 2 + 8*16*20 * 4;  // 124928
    hipFuncSetAttribute((const void*)scan_k,
                        hipFuncAttributeMaxDynamicSharedMemorySize, ldsBytes);
    scan_k<<<dim3(256), 512, ldsBytes, stream>>>(
        Wih0, Whh0, Wih1, Whh1, bih0, bhh0, bih1, bhh1, c0in,
        Xb, h0buf, h1buf, H1all, outp + (size_t)TT * BH, barcnt);

    // gamma = H1all @ attW^T + attb  (bf16 out)
    gemm_bt_k<<<dim3(HH / 64, (TT * BB) / 64), 256, 0, stream>>>(
        H1all, HH, nullptr, 0, attWb, HH, attb, gammaA, nullptr, HH, 0);

    // scores -> softmax -> ct
    attn_k<<<dim3(BB, TT / 16), 256, 0, stream>>>(gammaA, ctx, ctall);

    // out = tanh([ct, h1] @ outW^T + outb)  (fp32 out -> d_out)
    gemm_bt_k<<<dim3(HH / 64, (TT * BB) / 64), 256, 0, stream>>>(
        ctall, HH, H1all, HH, outWb, 2 * HH, outb, nullptr, outp, HH, 1);
}

// Round 4
// 4297.085 us; speedup vs baseline: 1.6487x; 1.2180x over previous
//
#include <hip/hip_runtime.h>

// Problem constants: T=128, B=128, S=128, H=1024, E=512, V=32000, L=2
#define TT 128
#define BB 128
#define SS 128
#define HH 1024
#define EE 512
#define BH (BB*HH)   // 131072

typedef unsigned short u16;                                   // bf16 bits
typedef __attribute__((ext_vector_type(8))) short s8v;        // MFMA A/B fragment (8 bf16)
typedef __attribute__((ext_vector_type(4))) float f32x4;      // MFMA C/D fragment

__device__ __forceinline__ float b2f(u16 u) {
    union { unsigned int i; float f; } v; v.i = ((unsigned int)u) << 16; return v.f;
}
__device__ __forceinline__ u16 f2b(float f) {
    union { float f; unsigned int i; } v; v.f = f;
    unsigned int x = v.i;
    x = x + 0x7fffu + ((x >> 16) & 1u);   // round-to-nearest-even
    return (u16)(x >> 16);
}
__device__ __forceinline__ float sigm(float x) {
    float t = __expf(-fabsf(x));
    float p = 1.0f / (1.0f + t);
    return x >= 0.0f ? p : 1.0f - p;
}
__device__ __forceinline__ float tanh_(float x) {
    float t = __expf(-2.0f * fabsf(x));
    float r = (1.0f - t) / (1.0f + t);
    return x >= 0.0f ? r : -r;
}

#define MFMA(a, b, c) __builtin_amdgcn_mfma_f32_16x16x32_bf16((a), (b), (c), 0, 0, 0)

// ---------------------------------------------------------------------------
// fp32 -> bf16 bulk convert (n multiple of 4)
// ---------------------------------------------------------------------------
__global__ __launch_bounds__(256)
void cvt_k(const float* __restrict__ s, u16* __restrict__ d, int n)
{
    const int i = (blockIdx.x * 256 + threadIdx.x) * 4;
    if (i < n) {
        const float4 v = *(const float4*)(s + i);
        ushort4 o;
        o.x = f2b(v.x); o.y = f2b(v.y); o.z = f2b(v.z); o.w = f2b(v.w);
        *(ushort4*)(d + i) = o;
    }
}

// ---------------------------------------------------------------------------
// Embedding gather + cast: X[t*B+b, :] = bf16(emb[toks[t,b], :])
// ---------------------------------------------------------------------------
__global__ __launch_bounds__(128)
void gather_k(const int* __restrict__ toks, const float* __restrict__ emb,
              u16* __restrict__ X)
{
    const int row = blockIdx.x;
    const int tok = toks[row];
    const int c = threadIdx.x * 4;
    const float4 v = *(const float4*)(emb + (size_t)tok * EE + c);
    ushort4 o;
    o.x = f2b(v.x); o.y = f2b(v.y); o.z = f2b(v.z); o.w = f2b(v.w);
    *(ushort4*)(X + (size_t)row * EE + c) = o;
}

// ---------------------------------------------------------------------------
// init: h0ring slot0 <- bf16(h0 layer0); h1init <- bf16(h0 layer1); barcnt=0
// ---------------------------------------------------------------------------
__global__ __launch_bounds__(256)
void init_k(const float* __restrict__ h0in,
            u16* __restrict__ h0ring, u16* __restrict__ h1init,
            int* __restrict__ barcnt)
{
    const int i = blockIdx.x * 256 + threadIdx.x;   // [0, 2*BH)
    const u16 hb = f2b(h0in[i]);
    if (i < BH) h0ring[i] = hb;
    else        h1init[i - BH] = hb;
    if (i == 0) *barcnt = 0;
}

// ---------------------------------------------------------------------------
// Persistent fused 2-layer LSTM scan. 256 blocks (1/CU) x 512 threads.
// Weights LDS-resident. h-state flows through WRITE-ONCE ring buffers
// (h0ring[129 slots], H1all doubles as the h1 ring), so readers use plain
// cached loads with NO cache invalidation: a ring address was never cached
// locally, so the load misses L1/L2 and fetches from LLC, which is fresh
// because each writer's RELEASE atomic-add drained vmcnt and wrote back its
// XCD L2 first. Within an XCD the 32 blocks then share the line via L2.
// Column swizzle: same-XCD blocks (assuming bk%8 XCD round-robin — perf
// heuristic only) own contiguous columns so h-writes form whole 128B lines.
// ---------------------------------------------------------------------------
__global__ __launch_bounds__(512, 1)
void scan_k(const float* __restrict__ Wih0, const float* __restrict__ Whh0,
            const float* __restrict__ Wih1, const float* __restrict__ Whh1,
            const float* __restrict__ bih0, const float* __restrict__ bhh0,
            const float* __restrict__ bih1, const float* __restrict__ bhh1,
            const float* __restrict__ c0in,
            const u16* __restrict__ Xb,
            u16* __restrict__ h0ring,   // 129 slots of BH (slot 0 = init)
            const u16* __restrict__ h1init,
            u16* __restrict__ H1all,    // T * BH (= h1 ring, slot t = step t)
            float* __restrict__ outT,   // d_out + T*BH: [hT (2BH), cT (2BH)]
            int* __restrict__ barcnt)
{
    extern __shared__ u16 lds[];
    u16* W0x = lds;                     // 16*4*16*8  =  8192 u16 (16 KB)
    u16* W0h = W0x + 16*4*16*8;         // 32*4*16*8  = 16384 u16 (32 KB)
    u16* W1x = W0h + 32*4*16*8;         //            = 16384 u16 (32 KB)
    u16* W1h = W1x + 32*4*16*8;         //            = 16384 u16 (32 KB)
    float* gst = (float*)(W1h + 32*4*16*8);  // 8*16*20 = 2560 fp32 (10 KB)

    const int tid  = threadIdx.x;
    const int bk   = blockIdx.x;
    // swizzle: XCD (bk&7) owns contiguous 128-col span
    const int j0   = (((bk & 7) << 5) | (bk >> 3)) * 4;
    const int lane = tid & 63;
    const int w    = tid >> 6;          // wave 0..7  (m-tile = w)
    const int l15  = lane & 15, quad = lane >> 4;

    // ---- one-time: weights -> LDS (fp32 -> bf16, swizzled) ----
    auto loadW = [&](const float* src, int K, u16* dst) {
        const int ntup = (K / 32) * 4 * 16;
        for (int idx = tid; idx < ntup; idx += 512) {
            const int n = idx & 15, q = (idx >> 4) & 3, kc = idx >> 6;
            const int col = ((n >> 2) * HH) + j0 + (n & 3);   // gate*H + j
            const float* sp = src + (size_t)col * K + kc * 32 + q * 8;
            const float4 v0 = *(const float4*)(sp);
            const float4 v1 = *(const float4*)(sp + 4);
            u16* dp = dst + (size_t)idx * 8;
            dp[0] = f2b(v0.x); dp[1] = f2b(v0.y); dp[2] = f2b(v0.z); dp[3] = f2b(v0.w);
            dp[4] = f2b(v1.x); dp[5] = f2b(v1.y); dp[6] = f2b(v1.z); dp[7] = f2b(v1.w);
        }
    };
    loadW(Wih0, EE, W0x);
    loadW(Whh0, HH, W0h);
    loadW(Wih1, HH, W1x);
    loadW(Whh1, HH, W1h);

    // pointwise thread mapping: tid -> (row, output col)
    const int prow = tid >> 2;          // 0..127
    const int pjj  = tid & 3;
    const int pj   = j0 + pjj;
    const int pw   = prow >> 4, pr16 = prow & 15;

    float c0 = c0in[(size_t)0 * BH + (size_t)prow * HH + pj];
    float c1 = c0in[(size_t)1 * BH + (size_t)prow * HH + pj];
    float b0[4], b1[4];
    #pragma unroll
    for (int g = 0; g < 4; ++g) {
        b0[g] = bih0[g * HH + pj] + bhh0[g * HH + pj];
        b1[g] = bih1[g * HH + pj] + bhh1[g * HH + pj];
    }

    __syncthreads();   // LDS weights ready

    const int arow = w * 16 + l15;      // this lane's A-row (batch row)

    for (int p = 0; p <= TT; ++p) {
        f32x4 acc0 = (f32x4)0.0f, acc1 = (f32x4)0.0f;

        // (a) x-part of layer 0 — static data, runs before the barrier wait
        if (p < TT) {
            const u16* ap = Xb + ((size_t)p * BB + arow) * EE + quad * 8;
            #pragma unroll 8
            for (int kc = 0; kc < 16; ++kc) {
                s8v a = *(const s8v*)(ap + kc * 32);
                s8v b = *(const s8v*)(W0x + ((size_t)(kc * 4 + quad) * 16 + l15) * 8);
                acc0 = MFMA(a, b, acc0);
            }
        }

        // (b) wait for previous phase's writers (no cache invalidation:
        //     ring addresses below were never locally cached)
        if (p > 0) {
            if (tid == 0) {
                const int target = 256 * p;
                while (__hip_atomic_load(barcnt, __ATOMIC_RELAXED,
                                         __HIP_MEMORY_SCOPE_AGENT) < target) {
                    __builtin_amdgcn_s_sleep(2);
                }
            }
            __syncthreads();
            asm volatile("" ::: "memory");   // compiler-only fence
        }

        // (c) h-dependent GEMMs (plain cached loads; L2-shared per XCD)
        const u16* h0p = h0ring + (size_t)p * BH;   // h0^{(p)}
        {
            const u16* ap = h0p + (size_t)arow * HH + quad * 8;
            if (p == 0) {
                #pragma unroll 8
                for (int kc = 0; kc < 32; ++kc) {
                    s8v a = *(const s8v*)(ap + kc * 32);
                    s8v b = *(const s8v*)(W0h + ((size_t)(kc * 4 + quad) * 16 + l15) * 8);
                    acc0 = MFMA(a, b, acc0);
                }
            } else if (p == TT) {
                #pragma unroll 8
                for (int kc = 0; kc < 32; ++kc) {
                    s8v a = *(const s8v*)(ap + kc * 32);
                    s8v b = *(const s8v*)(W1x + ((size_t)(kc * 4 + quad) * 16 + l15) * 8);
                    acc1 = MFMA(a, b, acc1);
                }
            } else {
                #pragma unroll 8
                for (int kc = 0; kc < 32; ++kc) {
                    s8v a = *(const s8v*)(ap + kc * 32);
                    s8v b0v = *(const s8v*)(W0h + ((size_t)(kc * 4 + quad) * 16 + l15) * 8);
                    s8v b1v = *(const s8v*)(W1x + ((size_t)(kc * 4 + quad) * 16 + l15) * 8);
                    acc0 = MFMA(a, b0v, acc0);
                    acc1 = MFMA(a, b1v, acc1);
                }
            }
        }
        if (p > 0) {   // h1 recurrence: h1^{(p-2)} = H1all[p-2] (or h1init)
            const u16* h1p = (p == 1) ? h1init : (H1all + (size_t)(p - 2) * BH);
            const u16* ap = h1p + (size_t)arow * HH + quad * 8;
            #pragma unroll 8
            for (int kc = 0; kc < 32; ++kc) {
                s8v a = *(const s8v*)(ap + kc * 32);
                s8v b = *(const s8v*)(W1h + ((size_t)(kc * 4 + quad) * 16 + l15) * 8);
                acc1 = MFMA(a, b, acc1);
            }
        }

        // (d) pointwise — layer 0 (writes h0ring slot p+1)
        if (p < TT) {
            #pragma unroll
            for (int r = 0; r < 4; ++r)
                gst[w * 320 + (quad * 4 + r) * 20 + l15] = acc0[r];
            __syncthreads();
            const float* gr = gst + pw * 320 + pr16 * 20;
            const float gi = gr[0 + pjj]  + b0[0];
            const float gf = gr[4 + pjj]  + b0[1];
            const float gg = gr[8 + pjj]  + b0[2];
            const float go = gr[12 + pjj] + b0[3];
            c0 = sigm(gf) * c0 + sigm(gi) * tanh_(gg);
            const float h = sigm(go) * tanh_(c0);
            h0ring[(size_t)(p + 1) * BH + (size_t)prow * HH + pj] = f2b(h);
            if (p == TT - 1) {
                outT[(size_t)0 * BH + (size_t)prow * HH + pj] = h;    // hT layer0
                outT[(size_t)2 * BH + (size_t)prow * HH + pj] = c0;   // cT layer0
            }
            __syncthreads();   // before gst reuse
        }
        // pointwise — layer 1 (writes H1all slot p-1)
        if (p > 0) {
            #pragma unroll
            for (int r = 0; r < 4; ++r)
                gst[w * 320 + (quad * 4 + r) * 20 + l15] = acc1[r];
            __syncthreads();
            const float* gr = gst + pw * 320 + pr16 * 20;
            const float gi = gr[0 + pjj]  + b1[0];
            const float gf = gr[4 + pjj]  + b1[1];
            const float gg = gr[8 + pjj]  + b1[2];
            const float go = gr[12 + pjj] + b1[3];
            c1 = sigm(gf) * c1 + sigm(gi) * tanh_(gg);
            const float h = sigm(go) * tanh_(c1);
            H1all[(size_t)(p - 1) * BH + (size_t)prow * HH + pj] = f2b(h);
            if (p == TT) {
                outT[(size_t)1 * BH + (size_t)prow * HH + pj] = h;    // hT layer1
                outT[(size_t)3 * BH + (size_t)prow * HH + pj] = c1;   // cT layer1
            }
            __syncthreads();
        }

        // (e) arrive: RELEASE = vmcnt drain + XCD-L2 writeback, then add
        if (p < TT && tid == 0) {
            __hip_atomic_fetch_add(barcnt, 1, __ATOMIC_RELEASE,
                                   __HIP_MEMORY_SCOPE_AGENT);
        }
    }
}

// ---------------------------------------------------------------------------
// C[M,N] = act(A1 @ W[:, :K1]^T + A2 @ W[:, K1:]^T + bias)
// A/W bf16, bias fp32. Out: bf16 (Cb) or fp32 (Cf). Tile 64x64, 4 waves.
// ---------------------------------------------------------------------------
__global__ __launch_bounds__(256)
void gemm_bt_k(const u16* __restrict__ A1, int K1,
               const u16* __restrict__ A2, int K2,
               const u16* __restrict__ W, int ldw,
               const float* __restrict__ bias,
               u16* __restrict__ Cb, float* __restrict__ Cf,
               int N, int act)
{
    const int lane = threadIdx.x & 63;
    const int wave = threadIdx.x >> 6;
    const int l15 = lane & 15, quad = lane >> 4;
    const int n0 = blockIdx.x * 64;
    const int mrow = blockIdx.y * 64 + wave * 16;
    const int arow = mrow + l15;

    f32x4 acc[4];
    #pragma unroll
    for (int nt = 0; nt < 4; ++nt) acc[nt] = (f32x4)0.0f;

    const u16* wr0 = W + (size_t)(n0 + 0 * 16 + l15) * ldw + quad * 8;
    const u16* wr1 = W + (size_t)(n0 + 1 * 16 + l15) * ldw + quad * 8;
    const u16* wr2 = W + (size_t)(n0 + 2 * 16 + l15) * ldw + quad * 8;
    const u16* wr3 = W + (size_t)(n0 + 3 * 16 + l15) * ldw + quad * 8;

    {
        const u16* ap = A1 + (size_t)arow * K1 + quad * 8;
        #pragma unroll 4
        for (int kk = 0; kk < K1; kk += 32) {
            s8v a = *(const s8v*)(ap + kk);
            acc[0] = MFMA(a, *(const s8v*)(wr0 + kk), acc[0]);
            acc[1] = MFMA(a, *(const s8v*)(wr1 + kk), acc[1]);
            acc[2] = MFMA(a, *(const s8v*)(wr2 + kk), acc[2]);
            acc[3] = MFMA(a, *(const s8v*)(wr3 + kk), acc[3]);
        }
    }
    if (A2 != nullptr) {
        const u16* ap = A2 + (size_t)arow * K2 + quad * 8;
        #pragma unroll 4
        for (int kk = 0; kk < K2; kk += 32) {
            s8v a = *(const s8v*)(ap + kk);
            acc[0] = MFMA(a, *(const s8v*)(wr0 + K1 + kk), acc[0]);
            acc[1] = MFMA(a, *(const s8v*)(wr1 + K1 + kk), acc[1]);
            acc[2] = MFMA(a, *(const s8v*)(wr2 + K1 + kk), acc[2]);
            acc[3] = MFMA(a, *(const s8v*)(wr3 + K1 + kk), acc[3]);
        }
    }
    #pragma unroll
    for (int nt = 0; nt < 4; ++nt) {
        const int col = n0 + nt * 16 + l15;
        const float bv = bias[col];
        #pragma unroll
        for (int r = 0; r < 4; ++r) {
            const int row = mrow + quad * 4 + r;
            float v = acc[nt][r] + bv;
            if (act) v = tanh_(v);
            if (Cf) Cf[(size_t)row * N + col] = v;
            else    Cb[(size_t)row * N + col] = f2b(v);
        }
    }
}

// ---------------------------------------------------------------------------
// Attention: per block (b, 16-t chunk): scores = gamma @ ctx^T (MFMA, ctx
// cast on the fly), softmax over S in LDS, ct = w @ ctx (fp32 vector).
// ---------------------------------------------------------------------------
__global__ __launch_bounds__(256)
void attn_k(const u16* __restrict__ gamma, const float* __restrict__ ctx,
            u16* __restrict__ ctall)
{
    const int b = blockIdx.x;
    const int t0 = blockIdx.y * 16;
    const int tid = threadIdx.x;
    const int lane = tid & 63, wave = tid >> 6;
    const int l15 = lane & 15, quad = lane >> 4;

    __shared__ float sw[16 * SS];

    {
        f32x4 acc0 = (f32x4)0.0f, acc1 = (f32x4)0.0f;
        const u16*   ap  = gamma + ((size_t)(t0 + l15) * BB + b) * HH + quad * 8;
        const float* bp0 = ctx + ((size_t)b * SS + (wave * 32 + l15)) * HH + quad * 8;
        const float* bp1 = ctx + ((size_t)b * SS + (wave * 32 + 16 + l15)) * HH + quad * 8;
        for (int kk = 0; kk < HH; kk += 32) {
            s8v a = *(const s8v*)(ap + kk);
            float4 u0 = *(const float4*)(bp0 + kk);
            float4 u1 = *(const float4*)(bp0 + kk + 4);
            s8v bv;
            bv[0] = (short)f2b(u0.x); bv[1] = (short)f2b(u0.y);
            bv[2] = (short)f2b(u0.z); bv[3] = (short)f2b(u0.w);
            bv[4] = (short)f2b(u1.x); bv[5] = (short)f2b(u1.y);
            bv[6] = (short)f2b(u1.z); bv[7] = (short)f2b(u1.w);
            acc0 = MFMA(a, bv, acc0);
            float4 w0 = *(const float4*)(bp1 + kk);
            float4 w1 = *(const float4*)(bp1 + kk + 4);
            s8v cv;
            cv[0] = (short)f2b(w0.x); cv[1] = (short)f2b(w0.y);
            cv[2] = (short)f2b(w0.z); cv[3] = (short)f2b(w0.w);
            cv[4] = (short)f2b(w1.x); cv[5] = (short)f2b(w1.y);
            cv[6] = (short)f2b(w1.z); cv[7] = (short)f2b(w1.w);
            acc1 = MFMA(a, cv, acc1);
        }
        #pragma unroll
        for (int r = 0; r < 4; ++r) {
            const int trow = quad * 4 + r;
            sw[trow * SS + wave * 32 + l15] = acc0[r];
            sw[trow * SS + wave * 32 + 16 + l15] = acc1[r];
        }
    }
    __syncthreads();

    {
        const int row = tid >> 4, c0 = tid & 15;
        float e[8];
        float m = -1e30f;
        #pragma unroll
        for (int k = 0; k < 8; ++k) { e[k] = sw[row * SS + c0 + k * 16]; m = fmaxf(m, e[k]); }
        #pragma unroll
        for (int off = 8; off >= 1; off >>= 1) m = fmaxf(m, __shfl_xor(m, off));
        float s = 0.0f;
        #pragma unroll
        for (int k = 0; k < 8; ++k) { e[k] = __expf(e[k] - m); s += e[k]; }
        #pragma unroll
        for (int off = 8; off >= 1; off >>= 1) s += __shfl_xor(s, off);
        const float inv = 1.0f / s;
        #pragma unroll
        for (int k = 0; k < 8; ++k) sw[row * SS + c0 + k * 16] = e[k] * inv;
    }
    __syncthreads();

    {
        const int h0 = tid * 4;
        float a[16][4];
        #pragma unroll
        for (int t = 0; t < 16; ++t)
            #pragma unroll
            for (int q = 0; q < 4; ++q) a[t][q] = 0.0f;

        const float* cp = ctx + (size_t)b * SS * HH + h0;
        for (int s = 0; s < SS; ++s) {
            const float4 cv = *(const float4*)(cp + (size_t)s * HH);
            #pragma unroll
            for (int t = 0; t < 16; ++t) {
                const float wgt = sw[t * SS + s];
                a[t][0] += wgt * cv.x;
                a[t][1] += wgt * cv.y;
                a[t][2] += wgt * cv.z;
                a[t][3] += wgt * cv.w;
            }
        }
        #pragma unroll
        for (int t = 0; t < 16; ++t) {
            u16* op = ctall + ((size_t)(t0 + t) * BB + b) * HH + h0;
            #pragma unroll
            for (int q = 0; q < 4; ++q) op[q] = f2b(a[t][q]);
        }
    }
}

// ---------------------------------------------------------------------------
extern "C" void kernel_launch(void* const* d_in, const int* in_sizes, int n_in,
                              void* d_out, int out_size, void* d_ws, size_t ws_size,
                              hipStream_t stream)
{
    const int*   toks = (const int*)d_in[0];
    const float* h0in = (const float*)d_in[1];
    const float* c0in = (const float*)d_in[2];
    const float* ctx  = (const float*)d_in[3];
    const float* emb  = (const float*)d_in[4];
    const float* Wih0 = (const float*)d_in[5];
    const float* Whh0 = (const float*)d_in[6];
    const float* bih0 = (const float*)d_in[7];
    const float* bhh0 = (const float*)d_in[8];
    const float* Wih1 = (const float*)d_in[9];
    const float* Whh1 = (const float*)d_in[10];
    const float* bih1 = (const float*)d_in[11];
    const float* bhh1 = (const float*)d_in[12];
    const float* attW = (const float*)d_in[13];
    const float* attb = (const float*)d_in[14];
    const float* outW = (const float*)d_in[15];
    const float* outb = (const float*)d_in[16];

    // workspace layout (~125 MB)
    u16*   h0ring = (u16*)d_ws;                          // 129*BH (write-once ring)
    u16*   h1init = h0ring + (size_t)(TT + 1) * BH;      // BH
    int*   barcnt = (int*)(h1init + BH);                 // 1 int (pad 64)
    u16*   Xb     = (u16*)(barcnt + 64);                 // T*B*E
    u16*   H1all  = Xb + (size_t)TT * BB * EE;           // T*BH (h1 ring + tail input)
    u16*   gammaA = H1all + (size_t)TT * BH;             // T*BH
    u16*   attWb  = gammaA + (size_t)TT * BH;            // H*H
    u16*   outWb  = attWb + (size_t)HH * HH;             // H*2H
    u16*   ctall  = h0ring;   // alias: scan is done before attn_k writes here

    // one-time conversions for the batched tail
    cvt_k<<<dim3((HH * HH / 4 + 255) / 256), 256, 0, stream>>>(attW, attWb, HH * HH);
    cvt_k<<<dim3((2 * HH * HH / 4 + 255) / 256), 256, 0, stream>>>(outW, outWb, 2 * HH * HH);

    gather_k<<<dim3(TT * BB), 128, 0, stream>>>(toks, emb, Xb);
    init_k<<<dim3(2 * BH / 256), 256, 0, stream>>>(h0in, h0ring, h1init, barcnt);

    // persistent fused LSTM scan (writes H1all + hT/cT tail of d_out)
    float* outp = (float*)d_out;
    const int ldsBytes = (16*4*16*8 + 3 * 32*4*16*8) * 2 + 8*16*20 * 4;  // 124928
    hipFuncSetAttribute((const void*)scan_k,
                        hipFuncAttributeMaxDynamicSharedMemorySize, ldsBytes);
    scan_k<<<dim3(256), 512, ldsBytes, stream>>>(
        Wih0, Whh0, Wih1, Whh1, bih0, bhh0, bih1, bhh1, c0in,
        Xb, h0ring, h1init, H1all, outp + (size_t)TT * BH, barcnt);

    // gamma = H1all @ attW^T + attb  (bf16 out)
    gemm_bt_k<<<dim3(HH / 64, (TT * BB) / 64), 256, 0, stream>>>(
        H1all, HH, nullptr, 0, attWb, HH, attb, gammaA, nullptr, HH, 0);

    // scores -> softmax -> ct
    attn_k<<<dim3(BB, TT / 16), 256, 0, stream>>>(gammaA, ctx, ctall);

    // out = tanh([ct, h1] @ outW^T + outb)  (fp32 out -> d_out)
    gemm_bt_k<<<dim3(HH / 64, (TT * BB) / 64), 256, 0, stream>>>(
        ctall, HH, H1all, HH, outWb, 2 * HH, outb, nullptr, outp, HH, 1);
}